// Round 6
// baseline (719.613 us; speedup 1.0000x reference)
//
#include <hip/hip_runtime.h>
#include <cstdint>
#include <cstddef>

// ---------------- problem constants ----------------
// B=16, L=128, E=256, H=256, RR=128, BIO=64, NT=3, V=30000, R=25

typedef __attribute__((ext_vector_type(8))) short short8;
typedef __attribute__((ext_vector_type(8))) int i32x8;
typedef __attribute__((ext_vector_type(4))) float f32x4;

__device__ __forceinline__ unsigned short f2bf(float f) {
  unsigned int u = __float_as_uint(f);
  u += 0x7fffu + ((u >> 16) & 1u);
  return (unsigned short)(u >> 16);
}
__device__ __forceinline__ float bf2f(unsigned short u) {
  return __uint_as_float(((unsigned int)u) << 16);
}

// ---------------- fused setup: embed + all weight prepacks + acc init ----------------
// W_hh -> fp8 B-frags for mfma_scale 16x16x128: frag f = nt*2+kt (nt 0..63, kt 0..1);
// lane holds 32 fp8 bytes: n = nt*16+(lane&15), k = kt*128 + (lane>>4)*32 + byte.
// (Exact within-lane k order cancels: A-frags packed with the same mapping.)
__device__ __forceinline__ void dev_pp8k128(const float* __restrict__ W,
                                            unsigned int* __restrict__ out, int idx) {
  int c = idx & 3;             // 8-byte chunk within lane's 32 bytes
  int lane = (idx >> 2) & 63;
  int f = idx >> 8;            // 0..127
  int nt = f >> 1, kt = f & 1;
  int n = nt * 16 + (lane & 15);
  int k0 = kt * 128 + (lane >> 4) * 32 + c * 8;
  const float* wp = &W[(size_t)n * 256 + k0];
  int lo = 0, hi = 0;
  lo = __builtin_amdgcn_cvt_pk_fp8_f32(wp[0], wp[1], lo, false);
  lo = __builtin_amdgcn_cvt_pk_fp8_f32(wp[2], wp[3], lo, true);
  hi = __builtin_amdgcn_cvt_pk_fp8_f32(wp[4], wp[5], hi, false);
  hi = __builtin_amdgcn_cvt_pk_fp8_f32(wp[6], wp[7], hi, true);
  size_t base = ((size_t)(f << 6) + lane) * 8 + (c << 1);
  out[base] = (unsigned)lo;
  out[base + 1] = (unsigned)hi;
}

__device__ __forceinline__ void dev_ppw(const float* __restrict__ W, int ldw, int nkt,
                                        uint4* __restrict__ out, int idx) {
  int lane = idx & 63;
  int f = idx >> 6;
  int kt = f % nkt;
  int nt = f / nkt;
  int row = nt * 16 + (lane & 15);
  int k0 = kt * 32 + ((lane >> 4) << 3);
  const float* wp = &W[(size_t)row * ldw + k0];
  union { unsigned short us[8]; uint4 v; } tmp;
#pragma unroll
  for (int j = 0; j < 8; ++j) tmp.us[j] = f2bf(wp[j]);
  out[idx] = tmp.v;
}

__global__ __launch_bounds__(256) void k_setup(
    const int* __restrict__ tok, const float* __restrict__ wemb,
    unsigned short* __restrict__ emb16,
    const float* __restrict__ Whhf, unsigned int* __restrict__ wpk8f,
    const float* __restrict__ Whhb, unsigned int* __restrict__ wpk8b,
    const float* __restrict__ Wihf, uint4* __restrict__ wihfPk,
    const float* __restrict__ Wihb, uint4* __restrict__ wihbPk,
    const float* __restrict__ suW, uint4* __restrict__ suPk,
    const float* __restrict__ svW, uint4* __restrict__ svPk,
    const float* __restrict__ suvW, uint4* __restrict__ w1Pk, uint4* __restrict__ w2Pk,
    float* __restrict__ acc) {
  int bid = blockIdx.x;
  int t = threadIdx.x;
  if (bid < 2048) {
    int w = tok[bid];
    emb16[bid * 256 + t] = f2bf(wemb[(size_t)w * 256 + t]);
  } else if (bid < 2176) {
    dev_pp8k128(Whhf, wpk8f, (bid - 2048) * 256 + t);
  } else if (bid < 2304) {
    dev_pp8k128(Whhb, wpk8b, (bid - 2176) * 256 + t);
  } else if (bid < 2432) {
    dev_ppw(Wihf, 256, 8, wihfPk, (bid - 2304) * 256 + t);
  } else if (bid < 2560) {
    dev_ppw(Wihb, 256, 8, wihbPk, (bid - 2432) * 256 + t);
  } else if (bid < 2580) {
    dev_ppw(suW, 320, 10, suPk, (bid - 2560) * 256 + t);
  } else if (bid < 2600) {
    dev_ppw(svW, 320, 10, svPk, (bid - 2580) * 256 + t);
  } else if (bid < 2608) {
    dev_ppw(suvW, 256, 4, w1Pk, (bid - 2600) * 256 + t);
  } else if (bid < 2616) {
    dev_ppw(suvW + 128, 256, 4, w2Pk, (bid - 2608) * 256 + t);
  } else {
    if (t < 16) acc[t] = 0.f;
  }
}

// ---------------- bf16 MFMA GEMM: C = act(A @ W^T + bias) ----------------
// PACKXG: write C in the lstm6 lane layout [t][nt(64)][col(16)][b(16)] bf16
// (rows are (b,l) flattened; b = row>>7, t = row&127).
template <bool RELU, bool BIAS, bool PACKXG>
__global__ __launch_bounds__(256) void k_bgemm(
    const unsigned short* __restrict__ A, const uint4* __restrict__ Wpk,
    const float* __restrict__ bias, unsigned short* __restrict__ C,
    const unsigned short* __restrict__ A2, const uint4* __restrict__ Wpk2,
    const float* __restrict__ bias2, unsigned short* __restrict__ C2,
    int M, int N, int K) {
  const unsigned short* Au = blockIdx.z ? A2 : A;
  const uint4* Wp = blockIdx.z ? Wpk2 : Wpk;
  const float* bi = blockIdx.z ? bias2 : bias;
  unsigned short* Co = blockIdx.z ? C2 : C;
  int nkt = K >> 5;
  int bn = blockIdx.x, bm = blockIdx.y;
  int tid = threadIdx.x;
  int w = tid >> 6;
  int lane = tid & 63;
  int m = lane & 15;
  int q = lane >> 4;
  int arow = bm * 64 + w * 16 + m;
  const unsigned short* Ap = Au + (size_t)arow * K + (q << 3);
  f32x4 z = {0.f, 0.f, 0.f, 0.f};
  f32x4 ac[4] = {z, z, z, z};
  for (int kt = 0; kt < nkt; ++kt) {
    uint4 a4 = *reinterpret_cast<const uint4*>(Ap + (kt << 5));
    short8 af = __builtin_bit_cast(short8, a4);
#pragma unroll
    for (int nt = 0; nt < 4; ++nt) {
      uint4 b4 = Wp[(size_t)(((bn << 2) + nt) * nkt + kt) * 64 + lane];
      ac[nt] = __builtin_amdgcn_mfma_f32_16x16x32_bf16(af, __builtin_bit_cast(short8, b4), ac[nt], 0, 0, 0);
    }
  }
#pragma unroll
  for (int nt = 0; nt < 4; ++nt) {
    int gnt = (bn << 2) + nt;
    int col = (gnt << 4) + m;
    float bv = BIAS ? bi[col] : 0.f;
#pragma unroll
    for (int reg = 0; reg < 4; ++reg) {
      int row = (bm << 6) + (w << 4) + (q << 2) + reg;
      float v = ac[nt][reg] + bv;
      if (RELU) v = fmaxf(v, 0.f);
      if (PACKXG) {
        int bb = row >> 7, tt = row & 127;
        Co[((size_t)(tt * 64 + gnt) * 16 + m) * 16 + bb] = f2bf(v);
      } else {
        Co[(size_t)row * N + col] = f2bf(v);
      }
    }
  }
}

// ---------------- LSTM v6: 2 blocks (one per dir), 512 threads, MX K=128 fp8 ----------
// Wave w owns j in [32w, 32w+32) for all 4 gates: n-tiles nt = g*16 + 2w + d (d=0,1).
// Weights resident: 16 frags x 8 VGPR = 128 VGPR/lane; amdgpu_waves_per_eu(2,2)
// sets the allocator budget to exactly 256 VGPR (8 waves/CU) + asm pin.
// C layout (16x16): row = q*4+reg = batch, col = lane&15 = j-within-tile ->
// all 4 gate values for one (b,j) land in the SAME lane/reg: no transpose at all.
// h fp8 in LDS (row pitch 272 B for uniform bank spread), double-buffered, 1 barrier/step.
__global__ void __launch_bounds__(512) __attribute__((amdgpu_waves_per_eu(2, 2)))
k_lstm6(const unsigned short* __restrict__ xgf, const unsigned short* __restrict__ xgb,
        const unsigned int* __restrict__ wpkf, const unsigned int* __restrict__ wpkb,
        unsigned short* __restrict__ hsf, unsigned short* __restrict__ hsb) {
  int dir = blockIdx.x;
  const unsigned short* xg = dir ? xgb : xgf;
  const unsigned int* wpk = dir ? wpkb : wpkf;
  unsigned short* hseq = dir ? hsb : hsf;

  __shared__ __align__(16) unsigned char h8[2][16 * 272];

  int tid = threadIdx.x;
  int w = tid >> 6;
  int lane = tid & 63;
  int m = lane & 15;   // A: batch row; C: j-col within tile
  int q = lane >> 4;

  // resident weights: [g][d][kt], 16 x 8 VGPR = 128 VGPR/lane
  i32x8 wfr[4][2][2];
#pragma unroll
  for (int g = 0; g < 4; ++g)
#pragma unroll
    for (int d = 0; d < 2; ++d)
#pragma unroll
      for (int kt = 0; kt < 2; ++kt) {
        int f = ((g * 16 + 2 * w + d) << 1) + kt;
        wfr[g][d][kt] = *reinterpret_cast<const i32x8*>(wpk + (((size_t)(f << 6) + lane) << 3));
      }
#pragma unroll
  for (int g = 0; g < 4; ++g)
#pragma unroll
    for (int d = 0; d < 2; ++d)
#pragma unroll
      for (int kt = 0; kt < 2; ++kt)
        asm volatile("" : "+v"(wfr[g][d][kt]));

  for (int i = tid; i < 2 * 16 * 272 / 4; i += 512) ((unsigned int*)&h8[0][0])[i] = 0;
  __syncthreads();

  float cst[8] = {0.f, 0.f, 0.f, 0.f, 0.f, 0.f, 0.f, 0.f};

  for (int s = 0; s < 128; ++s) {
    int t = dir ? (127 - s) : s;
    unsigned char* cur = h8[s & 1];
    unsigned char* nxt = h8[(s & 1) ^ 1];

    // xg: packed layout [t][nt][col=m][b]; lane reads its 4 batches (q*4..+3) per tile
    union { uint2 u; unsigned short s[4]; } xv[4][2];
    {
      const unsigned short* xb = xg + (size_t)t * 16384 + m * 16 + (q << 2);
#pragma unroll
      for (int g = 0; g < 4; ++g)
#pragma unroll
        for (int d = 0; d < 2; ++d) {
          int nt = g * 16 + 2 * w + d;
          xv[g][d].u = *reinterpret_cast<const uint2*>(xb + nt * 256);
        }
    }

    // A-frags: batch row m, 32 fp8 bytes at k = kt*128 + q*32
    i32x8 afr[2];
#pragma unroll
    for (int kt = 0; kt < 2; ++kt) {
      union { uint4 u[2]; i32x8 v; } tmp;
      const unsigned char* hp = cur + m * 272 + kt * 128 + q * 32;
      tmp.u[0] = *reinterpret_cast<const uint4*>(hp);
      tmp.u[1] = *reinterpret_cast<const uint4*>(hp + 16);
      afr[kt] = tmp.v;
    }

    f32x4 zz = {0.f, 0.f, 0.f, 0.f};
    f32x4 acg[4][2] = {{zz, zz}, {zz, zz}, {zz, zz}, {zz, zz}};
#pragma unroll
    for (int kt = 0; kt < 2; ++kt)
#pragma unroll
      for (int g = 0; g < 4; ++g)
#pragma unroll
        for (int d = 0; d < 2; ++d)
          acg[g][d] = __builtin_amdgcn_mfma_scale_f32_16x16x128_f8f6f4(
              afr[kt], wfr[g][d][kt], acg[g][d],
              0, 0,                     // cbsz=fp8(A), blgp=fp8(B)
              0, 0x7f7f7f7f,            // scale_a opsel, scale_a = 1.0 (E8M0 127)
              0, 0x7f7f7f7f);           // scale_b opsel, scale_b = 1.0

    // epilogue: lane owns (b = q*4+r, j = 32w + 16d + m), all 4 gates in-reg
#pragma unroll
    for (int d = 0; d < 2; ++d) {
#pragma unroll
      for (int r = 0; r < 4; ++r) {
        int b = (q << 2) + r;
        int j = (w << 5) + (d << 4) + m;
        float gi = acg[0][d][r] + bf2f(xv[0][d].s[r]);
        float gf = acg[1][d][r] + bf2f(xv[1][d].s[r]);
        float gg = acg[2][d][r] + bf2f(xv[2][d].s[r]);
        float go = acg[3][d][r] + bf2f(xv[3][d].s[r]);
        gi = fminf(fmaxf(gi, -30.f), 30.f);
        gf = fminf(fmaxf(gf, -30.f), 30.f);
        gg = fminf(fmaxf(gg, -30.f), 30.f);
        go = fminf(fmaxf(go, -30.f), 30.f);
        float si = __fdividef(1.f, 1.f + __expf(-gi));
        float sf = __fdividef(1.f, 1.f + __expf(-gf));
        float so = __fdividef(1.f, 1.f + __expf(-go));
        float eg = __expf(-2.f * gg);
        float tg = __fdividef(1.f - eg, 1.f + eg);
        float c = sf * cst[(d << 2) + r] + si * tg;
        cst[(d << 2) + r] = c;
        float cc = fminf(fmaxf(c, -30.f), 30.f);
        float ec = __expf(-2.f * cc);
        float th = __fdividef(1.f - ec, 1.f + ec);
        float h = so * th;
        hseq[(size_t)((b << 7) + t) * 256 + j] = f2bf(h);
        int pk = __builtin_amdgcn_cvt_pk_fp8_f32(h, h, 0, false);
        nxt[b * 272 + j] = (unsigned char)(pk & 0xff);
      }
    }
    __syncthreads();
  }
}

// ---------------- fused o/oc/emi: one block per (b,l) ----------------
__global__ __launch_bounds__(256) void k_ocemi(
    const unsigned short* __restrict__ hf16, const unsigned short* __restrict__ hb16,
    const int* __restrict__ bio, const float* __restrict__ bioE,
    const float* __restrict__ emiW, const float* __restrict__ emib,
    unsigned short* __restrict__ oc16, float* __restrict__ emi) {
  __shared__ float ol[256];
  int bl = blockIdx.x;
  int t = threadIdx.x;
  float v = 0.5f * (bf2f(hf16[bl * 256 + t]) + bf2f(hb16[bl * 256 + t]));
  ol[t] = v;
  oc16[bl * 320 + t] = f2bf(v);
  if (t < 64) oc16[bl * 320 + 256 + t] = f2bf(bioE[bio[bl] * 64 + t]);
  __syncthreads();
  if (t < 64) {
    float p0 = 0.f, p1 = 0.f, p2 = 0.f;
    for (int k = t; k < 256; k += 64) {
      float ov = ol[k];
      p0 += ov * emiW[k];
      p1 += ov * emiW[256 + k];
      p2 += ov * emiW[512 + k];
    }
#pragma unroll
    for (int off = 32; off; off >>= 1) {
      p0 += __shfl_down(p0, off);
      p1 += __shfl_down(p1, off);
      p2 += __shfl_down(p2, off);
    }
    if (t == 0) {
      emi[bl * 3 + 0] = p0 + emib[0];
      emi[bl * 3 + 1] = p1 + emib[1];
      emi[bl * 3 + 2] = p2 + emib[2];
    }
  }
}

// ---------------- fused loss: sel (blocks 0..1023) + crf (1024..1039) + finalize ----------------
__global__ __launch_bounds__(256) void k_loss(
    const unsigned short* __restrict__ a16, const unsigned short* __restrict__ c16,
    const float* __restrict__ suvb, const float* __restrict__ rel,
    const float* __restrict__ y, const int* __restrict__ tok,
    const float* __restrict__ emi, const int* __restrict__ bio,
    const float* __restrict__ cstart, const float* __restrict__ cend,
    const float* __restrict__ ctrans,
    float* __restrict__ acc, float* __restrict__ out) {
  int blk = blockIdx.x;
  int tid = threadIdx.x;
  if (blk < 1024) {
    __shared__ unsigned short alds[128][136];
    __shared__ float cbs[2][128];
    __shared__ float red[4];
    int b = blk >> 6;
    int ip = blk & 63;
    int hh = tid & 127;
    int half = tid >> 7;
    for (int j2 = half; j2 < 128; j2 += 2)
      alds[hh][j2] = a16[(size_t)((b << 7) + j2) * 128 + hh];
    {
      int i = (ip << 1) + half;
      cbs[half][hh] = bf2f(c16[(size_t)((b << 7) + i) * 128 + hh]) + suvb[hh];
    }
    __syncthreads();
    int i = (ip << 1) + half;
    int j = hh;
    float lg[25];
#pragma unroll
    for (int r = 0; r < 25; ++r) lg[r] = 0.f;
    for (int h = 0; h < 128; ++h) {
      float av = bf2f(alds[h][j]);
      float uv = fmaxf(av + cbs[half][h], 0.f);
#pragma unroll
      for (int r = 0; r < 25; ++r) lg[r] += uv * rel[r * 128 + h];
    }
    float mi = (tok[(b << 7) + i] != 0) ? 1.f : 0.f;
    float mj = (tok[(b << 7) + j] != 0) ? 1.f : 0.f;
    const float* yp = y + (size_t)((b << 7) + i) * 3200 + j;
    float bs = 0.f;
#pragma unroll
    for (int r = 0; r < 25; ++r) {
      float x = lg[r];
      float yv = yp[r * 128];
      bs += fmaxf(x, 0.f) - x * yv + __logf(1.f + __expf(-fabsf(x)));
    }
    bs *= mi * mj;
#pragma unroll
    for (int off = 32; off; off >>= 1) bs += __shfl_down(bs, off);
    if ((tid & 63) == 0) red[tid >> 6] = bs;
    __syncthreads();
    if (tid == 0) atomicAdd(&acc[0], red[0] + red[1] + red[2] + red[3]);
  } else {
    __shared__ float elds[128][4];
    __shared__ float msk[128];
    __shared__ int biol[128];
    __shared__ float r_t[2], r_m[2];
    int b = blk - 1024;
    int t = tid;
    if (t < 128) {
      biol[t] = bio[b * 128 + t];
      msk[t] = (tok[b * 128 + t] != 0) ? 1.f : 0.f;
#pragma unroll
      for (int g = 0; g < 3; ++g) elds[t][g] = emi[(b * 128 + t) * 3 + g];
    }
    __syncthreads();
    if (t < 128) {
      float m = msk[t];
      float term;
      if (t == 0)
        term = cstart[biol[0]] + elds[0][biol[0]];
      else
        term = (ctrans[biol[t - 1] * 3 + biol[t]] + elds[t][biol[t]]) * m;
      float ms = m;
#pragma unroll
      for (int off = 32; off; off >>= 1) {
        term += __shfl_down(term, off);
        ms += __shfl_down(ms, off);
      }
      if ((t & 63) == 0) { r_t[t >> 6] = term; r_m[t >> 6] = ms; }
    }
    __syncthreads();
    if (t == 0) {
      float num = r_t[0] + r_t[1];
      float msum = r_m[0] + r_m[1];
      int se = (int)msum - 1;
      if (se < 0) se = 0;
      num += cend[biol[se]];
      float tr[9];
#pragma unroll
      for (int i2 = 0; i2 < 9; ++i2) tr[i2] = ctrans[i2];
      float s0 = cstart[0] + elds[0][0];
      float s1 = cstart[1] + elds[0][1];
      float s2 = cstart[2] + elds[0][2];
      for (int tt = 1; tt < 128; ++tt) {
        float a0, a1, a2, mx, n0, n1, n2;
        a0 = s0 + tr[0]; a1 = s1 + tr[3]; a2 = s2 + tr[6];
        mx = fmaxf(a0, fmaxf(a1, a2));
        n0 = mx + __logf(__expf(a0 - mx) + __expf(a1 - mx) + __expf(a2 - mx)) + elds[tt][0];
        a0 = s0 + tr[1]; a1 = s1 + tr[4]; a2 = s2 + tr[7];
        mx = fmaxf(a0, fmaxf(a1, a2));
        n1 = mx + __logf(__expf(a0 - mx) + __expf(a1 - mx) + __expf(a2 - mx)) + elds[tt][1];
        a0 = s0 + tr[2]; a1 = s1 + tr[5]; a2 = s2 + tr[8];
        mx = fmaxf(a0, fmaxf(a1, a2));
        n2 = mx + __logf(__expf(a0 - mx) + __expf(a1 - mx) + __expf(a2 - mx)) + elds[tt][2];
        if (msk[tt] != 0.f) { s0 = n0; s1 = n1; s2 = n2; }
      }
      float a0 = s0 + cend[0], a1 = s1 + cend[1], a2 = s2 + cend[2];
      float mx = fmaxf(a0, fmaxf(a1, a2));
      float den = mx + __logf(__expf(a0 - mx) + __expf(a1 - mx) + __expf(a2 - mx));
      atomicAdd(&acc[1], num - den);
      atomicAdd(&acc[2], msum);
    }
  }
  if (tid == 0) {
    __threadfence();
    unsigned old = atomicAdd((unsigned int*)(acc + 5), 1u);
    if (old == 1039u) {
      __threadfence();
      float s0 = atomicAdd(&acc[0], 0.f);
      float s1 = atomicAdd(&acc[1], 0.f);
      float s2 = atomicAdd(&acc[2], 0.f);
      out[0] = -(s1 * (1.f / 16.f)) + s0 / s2;
    }
  }
}

// ---------------- host launcher ----------------
extern "C" void kernel_launch(void* const* d_in, const int* in_sizes, int n_in,
                              void* d_out, int out_size, void* d_ws, size_t ws_size,
                              hipStream_t stream) {
  const int* tokens = (const int*)d_in[0];
  const int* bio = (const int*)d_in[1];
  const float* selg = (const float*)d_in[2];
  const float* wemb = (const float*)d_in[3];
  const float* Wihf = (const float*)d_in[4];
  const float* Whhf = (const float*)d_in[5];
  const float* bf = (const float*)d_in[6];
  const float* Wihb = (const float*)d_in[7];
  const float* Whhb = (const float*)d_in[8];
  const float* bb = (const float*)d_in[9];
  const float* emiW = (const float*)d_in[10];
  const float* emib = (const float*)d_in[11];
  const float* bioE = (const float*)d_in[12];
  const float* suW = (const float*)d_in[13];
  const float* sub = (const float*)d_in[14];
  const float* svW = (const float*)d_in[15];
  const float* svb = (const float*)d_in[16];
  const float* suvW = (const float*)d_in[17];
  const float* suvb = (const float*)d_in[18];
  const float* rel = (const float*)d_in[19];
  const float* cstart = (const float*)d_in[20];
  const float* cend = (const float*)d_in[21];
  const float* ctrans = (const float*)d_in[22];

  float* ws = (float*)d_ws;
  float* emb16 = ws;                         // 262144 f (2048x256 bf16)
  float* xgfPk = emb16 + 262144;             // 1048576 f (packed xg bf16, fwd)
  float* xgbPk = xgfPk + 1048576;            // 1048576
  float* hf16 = xgbPk + 1048576;             // 262144 f (2048x256 bf16)
  float* hb16 = hf16 + 262144;               // 262144
  float* oc16 = hb16 + 262144;               // 327680 f (2048x320 bf16)
  float* u16 = oc16 + 327680;                // 131072 f (2048x128 bf16)
  float* v16 = u16 + 131072;                 // 131072
  float* a16 = v16 + 131072;                 // 131072
  float* c16 = a16 + 131072;                 // 131072
  float* emi = c16 + 131072;                 // 6144
  float* wpk8f = emi + 6144;                 // 65536 f (256 KB fp8 K=128 frags)
  float* wpk8b = wpk8f + 65536;              // 65536
  float* wihfPk = wpk8b + 65536;             // 131072 f (bf16 frags 1024x256)
  float* wihbPk = wihfPk + 131072;           // 131072
  float* suPk = wihbPk + 131072;             // 20480 f (128x320)
  float* svPk = suPk + 20480;                // 20480
  float* w1Pk = svPk + 20480;                // 8192 f (128x128)
  float* w2Pk = w1Pk + 8192;                 // 8192
  float* acc = w2Pk + 8192;                  // 16 (sums + completion counter)

  k_setup<<<2617, 256, 0, stream>>>(
      tokens, wemb, (unsigned short*)emb16,
      Whhf, (unsigned int*)wpk8f, Whhb, (unsigned int*)wpk8b,
      Wihf, (uint4*)wihfPk, Wihb, (uint4*)wihbPk,
      suW, (uint4*)suPk, svW, (uint4*)svPk,
      suvW, (uint4*)w1Pk, (uint4*)w2Pk, acc);

  // xg = emb @ W_ih^T + b  (both dirs via z), written in lstm6 packed layout
  k_bgemm<false, true, true><<<dim3(16, 32, 2), 256, 0, stream>>>(
      (const unsigned short*)emb16, (const uint4*)wihfPk, bf, (unsigned short*)xgfPk,
      (const unsigned short*)emb16, (const uint4*)wihbPk, bb, (unsigned short*)xgbPk,
      2048, 1024, 256);

  k_lstm6<<<2, 512, 0, stream>>>((const unsigned short*)xgfPk, (const unsigned short*)xgbPk,
                                 (const unsigned int*)wpk8f, (const unsigned int*)wpk8b,
                                 (unsigned short*)hf16, (unsigned short*)hb16);

  k_ocemi<<<2048, 256, 0, stream>>>((const unsigned short*)hf16, (const unsigned short*)hb16,
                                    bio, bioE, emiW, emib, (unsigned short*)oc16, emi);

  k_bgemm<true, true, false><<<dim3(2, 32, 2), 256, 0, stream>>>(
      (const unsigned short*)oc16, (const uint4*)suPk, sub, (unsigned short*)u16,
      (const unsigned short*)oc16, (const uint4*)svPk, svb, (unsigned short*)v16,
      2048, 128, 320);

  k_bgemm<false, false, false><<<dim3(2, 32, 2), 256, 0, stream>>>(
      (const unsigned short*)u16, (const uint4*)w1Pk, nullptr, (unsigned short*)a16,
      (const unsigned short*)v16, (const uint4*)w2Pk, nullptr, (unsigned short*)c16,
      2048, 128, 128);

  k_loss<<<1040, 256, 0, stream>>>((const unsigned short*)a16, (const unsigned short*)c16,
                                   suvb, rel, selg, tokens, emi, bio,
                                   cstart, cend, ctrans, acc, (float*)d_out);
}

// Round 7
// 446.340 us; speedup vs baseline: 1.6123x; 1.6123x over previous
//
#include <hip/hip_runtime.h>
#include <cstdint>
#include <cstddef>

// ---------------- problem constants ----------------
// B=16, L=128, E=256, H=256, RR=128, BIO=64, NT=3, V=30000, R=25

typedef __attribute__((ext_vector_type(8))) short short8;
typedef __attribute__((ext_vector_type(8))) int i32x8;
typedef __attribute__((ext_vector_type(4))) float f32x4;

__device__ __forceinline__ unsigned short f2bf(float f) {
  unsigned int u = __float_as_uint(f);
  u += 0x7fffu + ((u >> 16) & 1u);
  return (unsigned short)(u >> 16);
}
__device__ __forceinline__ float bf2f(unsigned short u) {
  return __uint_as_float(((unsigned int)u) << 16);
}

// ---------------- fused setup: embed + all weight prepacks + acc init ----------------
// W_hh -> fp8 B-frags for mfma_scale 16x16x128: frag f = nt*2+kt (nt 0..63, kt 0..1);
// lane holds 32 fp8 bytes: n = nt*16+(lane&15), k = kt*128 + (lane>>4)*32 + byte.
__device__ __forceinline__ void dev_pp8k128(const float* __restrict__ W,
                                            unsigned int* __restrict__ out, int idx) {
  int c = idx & 3;
  int lane = (idx >> 2) & 63;
  int f = idx >> 8;
  int nt = f >> 1, kt = f & 1;
  int n = nt * 16 + (lane & 15);
  int k0 = kt * 128 + (lane >> 4) * 32 + c * 8;
  const float* wp = &W[(size_t)n * 256 + k0];
  int lo = 0, hi = 0;
  lo = __builtin_amdgcn_cvt_pk_fp8_f32(wp[0], wp[1], lo, false);
  lo = __builtin_amdgcn_cvt_pk_fp8_f32(wp[2], wp[3], lo, true);
  hi = __builtin_amdgcn_cvt_pk_fp8_f32(wp[4], wp[5], hi, false);
  hi = __builtin_amdgcn_cvt_pk_fp8_f32(wp[6], wp[7], hi, true);
  size_t base = ((size_t)(f << 6) + lane) * 8 + (c << 1);
  out[base] = (unsigned)lo;
  out[base + 1] = (unsigned)hi;
}

__device__ __forceinline__ void dev_ppw(const float* __restrict__ W, int ldw, int nkt,
                                        uint4* __restrict__ out, int idx) {
  int lane = idx & 63;
  int f = idx >> 6;
  int kt = f % nkt;
  int nt = f / nkt;
  int row = nt * 16 + (lane & 15);
  int k0 = kt * 32 + ((lane >> 4) << 3);
  const float* wp = &W[(size_t)row * ldw + k0];
  union { unsigned short us[8]; uint4 v; } tmp;
#pragma unroll
  for (int j = 0; j < 8; ++j) tmp.us[j] = f2bf(wp[j]);
  out[idx] = tmp.v;
}

__global__ __launch_bounds__(256) void k_setup(
    const int* __restrict__ tok, const float* __restrict__ wemb,
    unsigned short* __restrict__ emb16,
    const float* __restrict__ Whhf, unsigned int* __restrict__ wpk8f,
    const float* __restrict__ Whhb, unsigned int* __restrict__ wpk8b,
    const float* __restrict__ Wihf, uint4* __restrict__ wihfPk,
    const float* __restrict__ Wihb, uint4* __restrict__ wihbPk,
    const float* __restrict__ suW, uint4* __restrict__ suPk,
    const float* __restrict__ svW, uint4* __restrict__ svPk,
    const float* __restrict__ suvW, uint4* __restrict__ w1Pk, uint4* __restrict__ w2Pk,
    float* __restrict__ acc) {
  int bid = blockIdx.x;
  int t = threadIdx.x;
  if (bid < 2048) {
    int w = tok[bid];
    emb16[bid * 256 + t] = f2bf(wemb[(size_t)w * 256 + t]);
  } else if (bid < 2176) {
    dev_pp8k128(Whhf, wpk8f, (bid - 2048) * 256 + t);
  } else if (bid < 2304) {
    dev_pp8k128(Whhb, wpk8b, (bid - 2176) * 256 + t);
  } else if (bid < 2432) {
    dev_ppw(Wihf, 256, 8, wihfPk, (bid - 2304) * 256 + t);
  } else if (bid < 2560) {
    dev_ppw(Wihb, 256, 8, wihbPk, (bid - 2432) * 256 + t);
  } else if (bid < 2580) {
    dev_ppw(suW, 320, 10, suPk, (bid - 2560) * 256 + t);
  } else if (bid < 2600) {
    dev_ppw(svW, 320, 10, svPk, (bid - 2580) * 256 + t);
  } else if (bid < 2608) {
    dev_ppw(suvW, 256, 4, w1Pk, (bid - 2600) * 256 + t);
  } else if (bid < 2616) {
    dev_ppw(suvW + 128, 256, 4, w2Pk, (bid - 2608) * 256 + t);
  } else {
    if (t < 16) acc[t] = 0.f;
  }
}

// ---------------- xg GEMM: xg = emb @ W_ih^T + b  (bf16, natural [row][1024]) -------
__global__ __launch_bounds__(256) void k_xg(
    const unsigned short* __restrict__ A,
    const uint4* __restrict__ Wpk, const float* __restrict__ bias,
    unsigned short* __restrict__ C,
    const uint4* __restrict__ Wpk2, const float* __restrict__ bias2,
    unsigned short* __restrict__ C2) {
  const uint4* Wp = blockIdx.z ? Wpk2 : Wpk;
  const float* bi = blockIdx.z ? bias2 : bias;
  unsigned short* Co = blockIdx.z ? C2 : C;
  int bn = blockIdx.x, bm = blockIdx.y;   // bn 0..15 (N=1024), bm 0..31 (M=2048)
  int tid = threadIdx.x;
  int w = tid >> 6;
  int lane = tid & 63;
  int m = lane & 15;
  int q = lane >> 4;
  int arow = bm * 64 + w * 16 + m;
  const unsigned short* Ap = A + (size_t)arow * 256 + (q << 3);
  f32x4 z = {0.f, 0.f, 0.f, 0.f};
  f32x4 ac[4] = {z, z, z, z};
  for (int kt = 0; kt < 8; ++kt) {
    uint4 a4 = *reinterpret_cast<const uint4*>(Ap + (kt << 5));
    short8 af = __builtin_bit_cast(short8, a4);
#pragma unroll
    for (int nt = 0; nt < 4; ++nt) {
      uint4 b4 = Wp[(size_t)(((bn << 2) + nt) * 8 + kt) * 64 + lane];
      ac[nt] = __builtin_amdgcn_mfma_f32_16x16x32_bf16(af, __builtin_bit_cast(short8, b4), ac[nt], 0, 0, 0);
    }
  }
#pragma unroll
  for (int nt = 0; nt < 4; ++nt) {
    int col = (bn << 6) + (nt << 4) + m;
    float bv = bi[col];
#pragma unroll
    for (int reg = 0; reg < 4; ++reg) {
      int row = (bm << 6) + (w << 4) + (q << 2) + reg;
      Co[(size_t)row * 1024 + col] = f2bf(ac[nt][reg] + bv);
    }
  }
}

// ---------------- LSTM v7: 32 blocks = (dir, batch), 1024 threads, MX K=128 --------
// Wave w (0..15) owns j in [16w,16w+16) for all 4 gates: nt = g*16 + w.
// Weights: 8 frags x 8 VGPR = 64 VGPR/lane -> fits UNDER the 128-VGPR tier
// (launch_bounds(1024,4) caps at 128; demand ~112 -> resident, no spill).
// C row 0 = batch (q==0,reg0); A row 0 = h (m==0 lanes read LDS, rest zero).
// One barrier/step; h fp8 double-buffered in LDS.
__global__ __launch_bounds__(1024, 4) void k_lstm7(
    const unsigned short* __restrict__ xgf, const unsigned short* __restrict__ xgb,
    const unsigned int* __restrict__ wpkf, const unsigned int* __restrict__ wpkb,
    unsigned short* __restrict__ hsf, unsigned short* __restrict__ hsb) {
  int bid = blockIdx.x;
  int dir = bid >> 4;
  int b = bid & 15;
  const unsigned short* xg = (dir ? xgb : xgf) + (size_t)b * 128 * 1024;
  const unsigned int* wpk = dir ? wpkb : wpkf;
  unsigned short* hseq = (dir ? hsb : hsf) + (size_t)b * 128 * 256;

  __shared__ __align__(16) unsigned char h8[2][16 * 272]; // only row 0 live; rows 1-15 zero

  int tid = threadIdx.x;
  int w = tid >> 6;   // wave 0..15 -> j-tile w
  int lane = tid & 63;
  int m = lane & 15;
  int q = lane >> 4;

  // resident weights: gate g, kt: frag f = (g*16+w)*2 + kt -> 8 x i32x8 = 64 VGPR
  i32x8 wfr[4][2];
#pragma unroll
  for (int g = 0; g < 4; ++g)
#pragma unroll
    for (int kt = 0; kt < 2; ++kt) {
      int f = (((g << 4) + w) << 1) + kt;
      wfr[g][kt] = *reinterpret_cast<const i32x8*>(wpk + (((size_t)(f << 6) + lane) << 3));
    }
#pragma unroll
  for (int g = 0; g < 4; ++g)
#pragma unroll
    for (int kt = 0; kt < 2; ++kt)
      asm volatile("" : "+v"(wfr[g][kt]));

  for (int i = tid; i < 2 * 16 * 272 / 4; i += 1024) ((unsigned int*)&h8[0][0])[i] = 0;
  __syncthreads();

  float cstate = 0.f;           // live on q==0 lanes; j = 16w + m
  int j = (w << 4) + m;

  for (int s = 0; s < 128; ++s) {
    int t = dir ? (127 - s) : s;
    const unsigned char* cur = h8[s & 1];
    unsigned char* nxt = h8[(s & 1) ^ 1];

    // xg gate biases for this step (q==0 lanes), 4 x bf16 scalar (coalesced per wave)
    float x0 = 0.f, x1 = 0.f, x2 = 0.f, x3 = 0.f;
    if (q == 0) {
      const unsigned short* xb = xg + (size_t)t * 1024 + j;
      x0 = bf2f(xb[0]);
      x1 = bf2f(xb[256]);
      x2 = bf2f(xb[512]);
      x3 = bf2f(xb[768]);
    }

    // A-frags: only m==0 lanes carry h (A row 0); 32 fp8 bytes at k = kt*128 + q*32
    i32x8 afr[2];
#pragma unroll
    for (int kt = 0; kt < 2; ++kt) {
      if (m == 0) {
        union { uint4 u[2]; i32x8 v; } tmp;
        const unsigned char* hp = cur + kt * 128 + q * 32;
        tmp.u[0] = *reinterpret_cast<const uint4*>(hp);
        tmp.u[1] = *reinterpret_cast<const uint4*>(hp + 16);
        afr[kt] = tmp.v;
      } else {
        afr[kt] = (i32x8){0, 0, 0, 0, 0, 0, 0, 0};
      }
    }

    f32x4 zz = {0.f, 0.f, 0.f, 0.f};
    f32x4 acg[4] = {zz, zz, zz, zz};
#pragma unroll
    for (int kt = 0; kt < 2; ++kt)
#pragma unroll
      for (int g = 0; g < 4; ++g)
        acg[g] = __builtin_amdgcn_mfma_scale_f32_16x16x128_f8f6f4(
            afr[kt], wfr[g][kt], acg[g],
            0, 0,                // cbsz=fp8(A), blgp=fp8(B)
            0, 0x7f7f7f7f,       // scale_a = 1.0 (E8M0 127)
            0, 0x7f7f7f7f);      // scale_b = 1.0

    // epilogue on q==0 lanes: batch row 0 -> acg[g][0]
    if (q == 0) {
      float gi = acg[0][0] + x0;
      float gf = acg[1][0] + x1;
      float gg = acg[2][0] + x2;
      float go = acg[3][0] + x3;
      gi = fminf(fmaxf(gi, -30.f), 30.f);
      gf = fminf(fmaxf(gf, -30.f), 30.f);
      gg = fminf(fmaxf(gg, -30.f), 30.f);
      go = fminf(fmaxf(go, -30.f), 30.f);
      float si = __fdividef(1.f, 1.f + __expf(-gi));
      float sf = __fdividef(1.f, 1.f + __expf(-gf));
      float so = __fdividef(1.f, 1.f + __expf(-go));
      float eg = __expf(-2.f * gg);
      float tg = __fdividef(1.f - eg, 1.f + eg);
      float c = sf * cstate + si * tg;
      cstate = c;
      float cc = fminf(fmaxf(c, -30.f), 30.f);
      float ec = __expf(-2.f * cc);
      float th = __fdividef(1.f - ec, 1.f + ec);
      float h = so * th;
      hseq[(size_t)t * 256 + j] = f2bf(h);
      int pk = __builtin_amdgcn_cvt_pk_fp8_f32(h, h, 0, false);
      nxt[j] = (unsigned char)(pk & 0xff);
    }
    __syncthreads();
  }
}

// ---------------- fused mid: oc -> emi, u, v, a, c (one block per 64 rows) ----------
__global__ __launch_bounds__(256) void k_mid(
    const unsigned short* __restrict__ hf16, const unsigned short* __restrict__ hb16,
    const int* __restrict__ bio, const float* __restrict__ bioE,
    const float* __restrict__ emiW, const float* __restrict__ emib,
    const uint4* __restrict__ suPk, const float* __restrict__ sub,
    const uint4* __restrict__ svPk, const float* __restrict__ svb,
    const uint4* __restrict__ w1Pk, const uint4* __restrict__ w2Pk,
    unsigned short* __restrict__ a16, unsigned short* __restrict__ c16,
    float* __restrict__ emi) {
  __shared__ __align__(16) unsigned short oc[64][328];   // bf16, rows r0..r0+63
  __shared__ __align__(16) unsigned short ub[64][136];
  __shared__ __align__(16) unsigned short vb[64][136];
  int r0 = blockIdx.x * 64;
  int tid = threadIdx.x;

  // stage oc = [0.5*(hf+hb) | bioE[bio]]
  for (int i = tid; i < 4096; i += 256) {      // 64 rows x 64 groups of 4 bf16
    int row = i >> 6, g4 = i & 63;
    uint2 af = *reinterpret_cast<const uint2*>(hf16 + (size_t)(r0 + row) * 256 + (g4 << 2));
    uint2 ab = *reinterpret_cast<const uint2*>(hb16 + (size_t)(r0 + row) * 256 + (g4 << 2));
    const unsigned short* pf = (const unsigned short*)&af;
    const unsigned short* pb = (const unsigned short*)&ab;
#pragma unroll
    for (int k = 0; k < 4; ++k)
      oc[row][(g4 << 2) + k] = f2bf(0.5f * (bf2f(pf[k]) + bf2f(pb[k])));
  }
  for (int i = tid; i < 1024; i += 256) {      // 64 rows x 16 groups of 4 (bio part)
    int row = i >> 4, g4 = i & 15;
    int bi = bio[r0 + row];
#pragma unroll
    for (int k = 0; k < 4; ++k)
      oc[row][256 + (g4 << 2) + k] = f2bf(bioE[bi * 64 + (g4 << 2) + k]);
  }
  __syncthreads();

  // emi: 192 threads, one (row, gate) dot each
  if (tid < 192) {
    int row = tid / 3, g = tid - row * 3;
    float accv = 0.f;
    const float* ew = emiW + g * 256;
    for (int k = 0; k < 256; k += 4) {
      accv += bf2f(oc[row][k]) * ew[k] + bf2f(oc[row][k + 1]) * ew[k + 1] +
              bf2f(oc[row][k + 2]) * ew[k + 2] + bf2f(oc[row][k + 3]) * ew[k + 3];
    }
    emi[(size_t)(r0 + row) * 3 + g] = accv + emib[g];
  }

  int w = tid >> 6, lane = tid & 63, m = lane & 15, q = lane >> 4;
  // u,v: A = oc rows [16w..16w+16), K=320 (kt=10), N=128 (nt=8)
  {
    f32x4 z = {0.f, 0.f, 0.f, 0.f};
    f32x4 au[8] = {z, z, z, z, z, z, z, z};
    f32x4 av[8] = {z, z, z, z, z, z, z, z};
    __syncthreads();
    for (int kt = 0; kt < 10; ++kt) {
      uint4 a4 = *reinterpret_cast<const uint4*>(&oc[(w << 4) + m][(kt << 5) + (q << 3)]);
      short8 af = __builtin_bit_cast(short8, a4);
#pragma unroll
      for (int nt = 0; nt < 8; ++nt) {
        uint4 bu = suPk[(size_t)(nt * 10 + kt) * 64 + lane];
        uint4 bv = svPk[(size_t)(nt * 10 + kt) * 64 + lane];
        au[nt] = __builtin_amdgcn_mfma_f32_16x16x32_bf16(af, __builtin_bit_cast(short8, bu), au[nt], 0, 0, 0);
        av[nt] = __builtin_amdgcn_mfma_f32_16x16x32_bf16(af, __builtin_bit_cast(short8, bv), av[nt], 0, 0, 0);
      }
    }
#pragma unroll
    for (int nt = 0; nt < 8; ++nt) {
      int col = (nt << 4) + m;
      float bu = sub[col], bv = svb[col];
#pragma unroll
      for (int reg = 0; reg < 4; ++reg) {
        int row = (w << 4) + (q << 2) + reg;
        ub[row][col] = f2bf(fmaxf(au[nt][reg] + bu, 0.f));
        vb[row][col] = f2bf(fmaxf(av[nt][reg] + bv, 0.f));
      }
    }
  }
  __syncthreads();

  // a = u@W1^T, c = v@W2^T: K=128 (kt=4), N=128 (nt=8)
  {
    f32x4 z = {0.f, 0.f, 0.f, 0.f};
    f32x4 aa[8] = {z, z, z, z, z, z, z, z};
    f32x4 ac[8] = {z, z, z, z, z, z, z, z};
    for (int kt = 0; kt < 4; ++kt) {
      uint4 ua = *reinterpret_cast<const uint4*>(&ub[(w << 4) + m][(kt << 5) + (q << 3)]);
      uint4 va = *reinterpret_cast<const uint4*>(&vb[(w << 4) + m][(kt << 5) + (q << 3)]);
      short8 uf = __builtin_bit_cast(short8, ua);
      short8 vf = __builtin_bit_cast(short8, va);
#pragma unroll
      for (int nt = 0; nt < 8; ++nt) {
        uint4 b1 = w1Pk[(size_t)((nt << 2) + kt) * 64 + lane];
        uint4 b2 = w2Pk[(size_t)((nt << 2) + kt) * 64 + lane];
        aa[nt] = __builtin_amdgcn_mfma_f32_16x16x32_bf16(uf, __builtin_bit_cast(short8, b1), aa[nt], 0, 0, 0);
        ac[nt] = __builtin_amdgcn_mfma_f32_16x16x32_bf16(vf, __builtin_bit_cast(short8, b2), ac[nt], 0, 0, 0);
      }
    }
#pragma unroll
    for (int nt = 0; nt < 8; ++nt) {
      int col = (nt << 4) + m;
#pragma unroll
      for (int reg = 0; reg < 4; ++reg) {
        int row = r0 + (w << 4) + (q << 2) + reg;
        a16[(size_t)row * 128 + col] = f2bf(aa[nt][reg]);
        c16[(size_t)row * 128 + col] = f2bf(ac[nt][reg]);
      }
    }
  }
}

// ---------------- fused loss: sel (blocks 0..1023) + crf (1024..1039) + finalize ----
__global__ __launch_bounds__(256) void k_loss(
    const unsigned short* __restrict__ a16, const unsigned short* __restrict__ c16,
    const float* __restrict__ suvb, const float* __restrict__ rel,
    const float* __restrict__ y, const int* __restrict__ tok,
    const float* __restrict__ emi, const int* __restrict__ bio,
    const float* __restrict__ cstart, const float* __restrict__ cend,
    const float* __restrict__ ctrans,
    float* __restrict__ acc, float* __restrict__ out) {
  int blk = blockIdx.x;
  int tid = threadIdx.x;
  if (blk < 1024) {
    __shared__ unsigned short alds[128][136];
    __shared__ float cbs[2][128];
    __shared__ float red[4];
    int b = blk >> 6;
    int ip = blk & 63;
    int hh = tid & 127;
    int half = tid >> 7;
    for (int j2 = half; j2 < 128; j2 += 2)
      alds[hh][j2] = a16[(size_t)((b << 7) + j2) * 128 + hh];
    {
      int i = (ip << 1) + half;
      cbs[half][hh] = bf2f(c16[(size_t)((b << 7) + i) * 128 + hh]) + suvb[hh];
    }
    __syncthreads();
    int i = (ip << 1) + half;
    int j = hh;
    float lg[25];
#pragma unroll
    for (int r = 0; r < 25; ++r) lg[r] = 0.f;
    for (int h = 0; h < 128; ++h) {
      float av = bf2f(alds[h][j]);
      float uv = fmaxf(av + cbs[half][h], 0.f);
#pragma unroll
      for (int r = 0; r < 25; ++r) lg[r] += uv * rel[r * 128 + h];
    }
    float mi = (tok[(b << 7) + i] != 0) ? 1.f : 0.f;
    float mj = (tok[(b << 7) + j] != 0) ? 1.f : 0.f;
    const float* yp = y + (size_t)((b << 7) + i) * 3200 + j;
    float bs = 0.f;
#pragma unroll
    for (int r = 0; r < 25; ++r) {
      float x = lg[r];
      float yv = yp[r * 128];
      bs += fmaxf(x, 0.f) - x * yv + __logf(1.f + __expf(-fabsf(x)));
    }
    bs *= mi * mj;
#pragma unroll
    for (int off = 32; off; off >>= 1) bs += __shfl_down(bs, off);
    if ((tid & 63) == 0) red[tid >> 6] = bs;
    __syncthreads();
    if (tid == 0) atomicAdd(&acc[0], red[0] + red[1] + red[2] + red[3]);
  } else {
    __shared__ float elds[128][4];
    __shared__ float msk[128];
    __shared__ int biol[128];
    __shared__ float r_t[2], r_m[2];
    int b = blk - 1024;
    int t = tid;
    if (t < 128) {
      biol[t] = bio[b * 128 + t];
      msk[t] = (tok[b * 128 + t] != 0) ? 1.f : 0.f;
#pragma unroll
      for (int g = 0; g < 3; ++g) elds[t][g] = emi[(b * 128 + t) * 3 + g];
    }
    __syncthreads();
    if (t < 128) {
      float m = msk[t];
      float term;
      if (t == 0)
        term = cstart[biol[0]] + elds[0][biol[0]];
      else
        term = (ctrans[biol[t - 1] * 3 + biol[t]] + elds[t][biol[t]]) * m;
      float ms = m;
#pragma unroll
      for (int off = 32; off; off >>= 1) {
        term += __shfl_down(term, off);
        ms += __shfl_down(ms, off);
      }
      if ((t & 63) == 0) { r_t[t >> 6] = term; r_m[t >> 6] = ms; }
    }
    __syncthreads();
    if (t == 0) {
      float num = r_t[0] + r_t[1];
      float msum = r_m[0] + r_m[1];
      int se = (int)msum - 1;
      if (se < 0) se = 0;
      num += cend[biol[se]];
      float tr[9];
#pragma unroll
      for (int i2 = 0; i2 < 9; ++i2) tr[i2] = ctrans[i2];
      float s0 = cstart[0] + elds[0][0];
      float s1 = cstart[1] + elds[0][1];
      float s2 = cstart[2] + elds[0][2];
      for (int tt = 1; tt < 128; ++tt) {
        float a0, a1, a2, mx, n0, n1, n2;
        a0 = s0 + tr[0]; a1 = s1 + tr[3]; a2 = s2 + tr[6];
        mx = fmaxf(a0, fmaxf(a1, a2));
        n0 = mx + __logf(__expf(a0 - mx) + __expf(a1 - mx) + __expf(a2 - mx)) + elds[tt][0];
        a0 = s0 + tr[1]; a1 = s1 + tr[4]; a2 = s2 + tr[7];
        mx = fmaxf(a0, fmaxf(a1, a2));
        n1 = mx + __logf(__expf(a0 - mx) + __expf(a1 - mx) + __expf(a2 - mx)) + elds[tt][1];
        a0 = s0 + tr[2]; a1 = s1 + tr[5]; a2 = s2 + tr[8];
        mx = fmaxf(a0, fmaxf(a1, a2));
        n2 = mx + __logf(__expf(a0 - mx) + __expf(a1 - mx) + __expf(a2 - mx)) + elds[tt][2];
        if (msk[tt] != 0.f) { s0 = n0; s1 = n1; s2 = n2; }
      }
      float a0 = s0 + cend[0], a1 = s1 + cend[1], a2 = s2 + cend[2];
      float mx = fmaxf(a0, fmaxf(a1, a2));
      float den = mx + __logf(__expf(a0 - mx) + __expf(a1 - mx) + __expf(a2 - mx));
      atomicAdd(&acc[1], num - den);
      atomicAdd(&acc[2], msum);
    }
  }
  if (tid == 0) {
    __threadfence();
    unsigned old = atomicAdd((unsigned int*)(acc + 5), 1u);
    if (old == 1039u) {
      __threadfence();
      float s0 = atomicAdd(&acc[0], 0.f);
      float s1 = atomicAdd(&acc[1], 0.f);
      float s2 = atomicAdd(&acc[2], 0.f);
      out[0] = -(s1 * (1.f / 16.f)) + s0 / s2;
    }
  }
}

// ---------------- host launcher ----------------
extern "C" void kernel_launch(void* const* d_in, const int* in_sizes, int n_in,
                              void* d_out, int out_size, void* d_ws, size_t ws_size,
                              hipStream_t stream) {
  const int* tokens = (const int*)d_in[0];
  const int* bio = (const int*)d_in[1];
  const float* selg = (const float*)d_in[2];
  const float* wemb = (const float*)d_in[3];
  const float* Wihf = (const float*)d_in[4];
  const float* Whhf = (const float*)d_in[5];
  const float* bf = (const float*)d_in[6];
  const float* Wihb = (const float*)d_in[7];
  const float* Whhb = (const float*)d_in[8];
  const float* bb = (const float*)d_in[9];
  const float* emiW = (const float*)d_in[10];
  const float* emib = (const float*)d_in[11];
  const float* bioE = (const float*)d_in[12];
  const float* suW = (const float*)d_in[13];
  const float* sub = (const float*)d_in[14];
  const float* svW = (const float*)d_in[15];
  const float* svb = (const float*)d_in[16];
  const float* suvW = (const float*)d_in[17];
  const float* suvb = (const float*)d_in[18];
  const float* rel = (const float*)d_in[19];
  const float* cstart = (const float*)d_in[20];
  const float* cend = (const float*)d_in[21];
  const float* ctrans = (const float*)d_in[22];

  float* ws = (float*)d_ws;
  float* emb16 = ws;                         // 262144 f (2048x256 bf16)
  float* xgf16 = emb16 + 262144;             // 1048576 f (2048x1024 bf16)
  float* xgb16 = xgf16 + 1048576;            // 1048576
  float* hf16 = xgb16 + 1048576;             // 262144 f (2048x256 bf16)
  float* hb16 = hf16 + 262144;               // 262144
  float* a16 = hb16 + 262144;                // 131072 f (2048x128 bf16)
  float* c16 = a16 + 131072;                 // 131072
  float* emi = c16 + 131072;                 // 6144
  float* wpk8f = emi + 6144;                 // 65536 f (256 KB fp8 K=128 frags)
  float* wpk8b = wpk8f + 65536;              // 65536
  float* wihfPk = wpk8b + 65536;             // 131072 f (bf16 frags 1024x256)
  float* wihbPk = wihfPk + 131072;           // 131072
  float* suPk = wihbPk + 131072;             // 20480 f (128x320)
  float* svPk = suPk + 20480;                // 20480
  float* w1Pk = svPk + 20480;                // 8192 f (128x128)
  float* w2Pk = w1Pk + 8192;                 // 8192
  float* acc = w2Pk + 8192;                  // 16 (sums + completion counter)

  k_setup<<<2617, 256, 0, stream>>>(
      tokens, wemb, (unsigned short*)emb16,
      Whhf, (unsigned int*)wpk8f, Whhb, (unsigned int*)wpk8b,
      Wihf, (uint4*)wihfPk, Wihb, (uint4*)wihbPk,
      suW, (uint4*)suPk, svW, (uint4*)svPk,
      suvW, (uint4*)w1Pk, (uint4*)w2Pk, acc);

  k_xg<<<dim3(16, 32, 2), 256, 0, stream>>>(
      (const unsigned short*)emb16,
      (const uint4*)wihfPk, bf, (unsigned short*)xgf16,
      (const uint4*)wihbPk, bb, (unsigned short*)xgb16);

  k_lstm7<<<32, 1024, 0, stream>>>(
      (const unsigned short*)xgf16, (const unsigned short*)xgb16,
      (const unsigned int*)wpk8f, (const unsigned int*)wpk8b,
      (unsigned short*)hf16, (unsigned short*)hb16);

  k_mid<<<32, 256, 0, stream>>>(
      (const unsigned short*)hf16, (const unsigned short*)hb16,
      bio, bioE, emiW, emib,
      (const uint4*)suPk, sub, (const uint4*)svPk, svb,
      (const uint4*)w1Pk, (const uint4*)w2Pk,
      (unsigned short*)a16, (unsigned short*)c16, emi);

  k_loss<<<1040, 256, 0, stream>>>((const unsigned short*)a16, (const unsigned short*)c16,
                                   suvb, rel, selg, tokens, emi, bio,
                                   cstart, cend, ctrans, acc, (float*)d_out);
}

// Round 8
// 394.383 us; speedup vs baseline: 1.8247x; 1.1317x over previous
//
#include <hip/hip_runtime.h>
#include <cstdint>
#include <cstddef>

// ---------------- problem constants ----------------
// B=16, L=128, E=256, H=256, RR=128, BIO=64, NT=3, V=30000, R=25

typedef __attribute__((ext_vector_type(8))) short short8;
typedef __attribute__((ext_vector_type(8))) int i32x8;
typedef __attribute__((ext_vector_type(4))) float f32x4;

__device__ __forceinline__ unsigned short f2bf(float f) {
  unsigned int u = __float_as_uint(f);
  u += 0x7fffu + ((u >> 16) & 1u);
  return (unsigned short)(u >> 16);
}
__device__ __forceinline__ float bf2f(unsigned short u) {
  return __uint_as_float(((unsigned int)u) << 16);
}

// ---------------- setup: weight prepacks + acc init (no embed anymore) ----------------
// W_hh -> fp8 B-frags for mfma_scale 16x16x128 (same as r6/r7, verified absmax 0)
__device__ __forceinline__ void dev_pp8k128(const float* __restrict__ W,
                                            unsigned int* __restrict__ out, int idx) {
  int c = idx & 3;
  int lane = (idx >> 2) & 63;
  int f = idx >> 8;
  int nt = f >> 1, kt = f & 1;
  int n = nt * 16 + (lane & 15);
  int k0 = kt * 128 + (lane >> 4) * 32 + c * 8;
  const float* wp = &W[(size_t)n * 256 + k0];
  int lo = 0, hi = 0;
  lo = __builtin_amdgcn_cvt_pk_fp8_f32(wp[0], wp[1], lo, false);
  lo = __builtin_amdgcn_cvt_pk_fp8_f32(wp[2], wp[3], lo, true);
  hi = __builtin_amdgcn_cvt_pk_fp8_f32(wp[4], wp[5], hi, false);
  hi = __builtin_amdgcn_cvt_pk_fp8_f32(wp[6], wp[7], hi, true);
  size_t base = ((size_t)(f << 6) + lane) * 8 + (c << 1);
  out[base] = (unsigned)lo;
  out[base + 1] = (unsigned)hi;
}

__device__ __forceinline__ void dev_ppw(const float* __restrict__ W, int ldw, int nkt,
                                        uint4* __restrict__ out, int idx) {
  int lane = idx & 63;
  int f = idx >> 6;
  int kt = f % nkt;
  int nt = f / nkt;
  int row = nt * 16 + (lane & 15);
  int k0 = kt * 32 + ((lane >> 4) << 3);
  const float* wp = &W[(size_t)row * ldw + k0];
  union { unsigned short us[8]; uint4 v; } tmp;
#pragma unroll
  for (int j = 0; j < 8; ++j) tmp.us[j] = f2bf(wp[j]);
  out[idx] = tmp.v;
}

__global__ __launch_bounds__(256) void k_setup(
    const float* __restrict__ Whhf, unsigned int* __restrict__ wpk8f,
    const float* __restrict__ Whhb, unsigned int* __restrict__ wpk8b,
    const float* __restrict__ Wihf, uint4* __restrict__ wihfPk,
    const float* __restrict__ Wihb, uint4* __restrict__ wihbPk,
    const float* __restrict__ suW, uint4* __restrict__ suPk,
    const float* __restrict__ svW, uint4* __restrict__ svPk,
    const float* __restrict__ suvW, uint4* __restrict__ w1Pk, uint4* __restrict__ w2Pk,
    float* __restrict__ acc) {
  int bid = blockIdx.x;
  int t = threadIdx.x;
  if (bid < 128) {
    dev_pp8k128(Whhf, wpk8f, bid * 256 + t);
  } else if (bid < 256) {
    dev_pp8k128(Whhb, wpk8b, (bid - 128) * 256 + t);
  } else if (bid < 384) {
    dev_ppw(Wihf, 256, 8, wihfPk, (bid - 256) * 256 + t);
  } else if (bid < 512) {
    dev_ppw(Wihb, 256, 8, wihbPk, (bid - 384) * 256 + t);
  } else if (bid < 532) {
    dev_ppw(suW, 320, 10, suPk, (bid - 512) * 256 + t);
  } else if (bid < 552) {
    dev_ppw(svW, 320, 10, svPk, (bid - 532) * 256 + t);
  } else if (bid < 560) {
    dev_ppw(suvW, 256, 4, w1Pk, (bid - 552) * 256 + t);
  } else if (bid < 568) {
    dev_ppw(suvW + 128, 256, 4, w2Pk, (bid - 560) * 256 + t);
  } else {
    if (t < 16) acc[t] = 0.f;
  }
}

// ---------------- xg GEMM with inline embedding gather ----------------
// xg = wemb[tok] @ W_ih^T + b, bf16 out, natural layout [b*128+t][1024]
__global__ __launch_bounds__(256) void k_xg(
    const int* __restrict__ tok, const float* __restrict__ wemb,
    const uint4* __restrict__ WpkF, const float* __restrict__ biasF,
    unsigned short* __restrict__ CF,
    const uint4* __restrict__ WpkB, const float* __restrict__ biasB,
    unsigned short* __restrict__ CB) {
  const uint4* Wp = blockIdx.z ? WpkB : WpkF;
  const float* bi = blockIdx.z ? biasB : biasF;
  unsigned short* Co = blockIdx.z ? CB : CF;
  int bn = blockIdx.x, bm = blockIdx.y;
  int tid = threadIdx.x;
  int w = tid >> 6;
  int lane = tid & 63;
  int m = lane & 15;
  int q = lane >> 4;
  int arow = bm * 64 + w * 16 + m;
  const float* ew = wemb + (size_t)tok[arow] * 256 + (q << 3);
  f32x4 z = {0.f, 0.f, 0.f, 0.f};
  f32x4 ac[4] = {z, z, z, z};
  for (int kt = 0; kt < 8; ++kt) {
    float4 e0 = *reinterpret_cast<const float4*>(ew + (kt << 5));
    float4 e1 = *reinterpret_cast<const float4*>(ew + (kt << 5) + 4);
    union { unsigned short us[8]; short8 v; } af;
    af.us[0] = f2bf(e0.x); af.us[1] = f2bf(e0.y); af.us[2] = f2bf(e0.z); af.us[3] = f2bf(e0.w);
    af.us[4] = f2bf(e1.x); af.us[5] = f2bf(e1.y); af.us[6] = f2bf(e1.z); af.us[7] = f2bf(e1.w);
#pragma unroll
    for (int nt = 0; nt < 4; ++nt) {
      uint4 b4 = Wp[(size_t)(((bn << 2) + nt) * 8 + kt) * 64 + lane];
      ac[nt] = __builtin_amdgcn_mfma_f32_16x16x32_bf16(af.v, __builtin_bit_cast(short8, b4), ac[nt], 0, 0, 0);
    }
  }
#pragma unroll
  for (int nt = 0; nt < 4; ++nt) {
    int col = (bn << 6) + (nt << 4) + m;
    float bv = bi[col];
#pragma unroll
    for (int reg = 0; reg < 4; ++reg) {
      int row = (bm << 6) + (w << 4) + (q << 2) + reg;
      Co[(size_t)row * 1024 + col] = f2bf(ac[nt][reg] + bv);
    }
  }
}

// ---------------- LSTM v8: 32 blocks = (dir,batch), 1024 thr, MX K=128 fp8 ---------
// r7 structure + global-free inner steps: xg staged in 8-step LDS chunks
// (register-prefetched -> vmcnt==0 at per-step barriers), h history buffered in
// LDS and flushed 4 KB/chunk coalesced. A-frags read unconditionally from a
// zeroed 16-row tile (no cndmask). Weights 64 VGPR/lane (AGPR-resident per r7).
__global__ __launch_bounds__(1024, 4) void k_lstm8(
    const unsigned short* __restrict__ xgf, const unsigned short* __restrict__ xgb,
    const unsigned int* __restrict__ wpkf, const unsigned int* __restrict__ wpkb,
    unsigned short* __restrict__ hsf, unsigned short* __restrict__ hsb) {
  int bid = blockIdx.x;
  int dir = bid >> 4;
  int b = bid & 15;
  const unsigned short* xg = (dir ? xgb : xgf) + (size_t)b * 128 * 1024;
  const unsigned int* wpk = dir ? wpkb : wpkf;
  unsigned short* hseq = (dir ? hsb : hsf) + (size_t)b * 128 * 256;

  __shared__ __align__(16) unsigned short xgl[8 * 1024];   // 16 KB xg chunk
  __shared__ __align__(16) unsigned short hfl[8 * 256];    // 4 KB h flush buffer
  __shared__ __align__(16) unsigned char h8[2][16 * 272];  // A-tiles; rows 1-15 stay 0

  int tid = threadIdx.x;
  int w = tid >> 6;
  int lane = tid & 63;
  int m = lane & 15;
  int q = lane >> 4;

  // resident weights: 8 x i32x8 = 64 VGPR/lane
  i32x8 wfr[4][2];
#pragma unroll
  for (int g = 0; g < 4; ++g)
#pragma unroll
    for (int kt = 0; kt < 2; ++kt) {
      int f = (((g << 4) + w) << 1) + kt;
      wfr[g][kt] = *reinterpret_cast<const i32x8*>(wpk + (((size_t)(f << 6) + lane) << 3));
    }
#pragma unroll
  for (int g = 0; g < 4; ++g)
#pragma unroll
    for (int kt = 0; kt < 2; ++kt)
      asm volatile("" : "+v"(wfr[g][kt]));

  for (int i = tid; i < 2 * 16 * 272 / 4; i += 1024) ((unsigned int*)&h8[0][0])[i] = 0;
  // preload chunk 0
  {
    int tb0 = dir ? 120 : 0;
    uint4 x0 = *reinterpret_cast<const uint4*>((const char*)xg + (size_t)tb0 * 2048 + tid * 16);
    reinterpret_cast<uint4*>(xgl)[tid] = x0;
  }
  __syncthreads();

  float cstate = 0.f;           // q==0 lanes own j = 16w + m
  int j = (w << 4) + m;

  for (int c = 0; c < 16; ++c) {
    int tbase = dir ? (120 - 8 * c) : (8 * c);
    uint4 xnext = {0, 0, 0, 0};
    if (c < 15) {
      int tb2 = dir ? (tbase - 8) : (tbase + 8);
      xnext = *reinterpret_cast<const uint4*>((const char*)xg + (size_t)tb2 * 2048 + tid * 16);
    }
#pragma unroll
    for (int i = 0; i < 8; ++i) {
      int s = 8 * c + i;
      int t = dir ? (127 - s) : s;
      int slot = t & 7;
      const unsigned char* cur = h8[s & 1];
      unsigned char* nxt = h8[(s & 1) ^ 1];

      float x0 = 0.f, x1 = 0.f, x2 = 0.f, x3 = 0.f;
      if (q == 0) {
        const unsigned short* xb = xgl + slot * 1024 + j;
        x0 = bf2f(xb[0]);
        x1 = bf2f(xb[256]);
        x2 = bf2f(xb[512]);
        x3 = bf2f(xb[768]);
      }

      // A-frags: all lanes read row m (rows 1-15 are zero -> zero contribution)
      i32x8 afr[2];
#pragma unroll
      for (int kt = 0; kt < 2; ++kt) {
        union { uint4 u[2]; i32x8 v; } tmp;
        const unsigned char* hp = cur + m * 272 + kt * 128 + q * 32;
        tmp.u[0] = *reinterpret_cast<const uint4*>(hp);
        tmp.u[1] = *reinterpret_cast<const uint4*>(hp + 16);
        afr[kt] = tmp.v;
      }

      f32x4 zz = {0.f, 0.f, 0.f, 0.f};
      f32x4 acg[4] = {zz, zz, zz, zz};
#pragma unroll
      for (int kt = 0; kt < 2; ++kt)
#pragma unroll
        for (int g = 0; g < 4; ++g)
          acg[g] = __builtin_amdgcn_mfma_scale_f32_16x16x128_f8f6f4(
              afr[kt], wfr[g][kt], acg[g],
              0, 0, 0, 0x7f7f7f7f, 0, 0x7f7f7f7f);

      if (q == 0) {
        float gi = acg[0][0] + x0;
        float gf = acg[1][0] + x1;
        float gg = acg[2][0] + x2;
        float go = acg[3][0] + x3;
        gi = fminf(fmaxf(gi, -30.f), 30.f);
        gf = fminf(fmaxf(gf, -30.f), 30.f);
        gg = fminf(fmaxf(gg, -30.f), 30.f);
        go = fminf(fmaxf(go, -30.f), 30.f);
        float si = __fdividef(1.f, 1.f + __expf(-gi));
        float sf = __fdividef(1.f, 1.f + __expf(-gf));
        float so = __fdividef(1.f, 1.f + __expf(-go));
        float eg = __expf(-2.f * gg);
        float tg = __fdividef(1.f - eg, 1.f + eg);
        float cc2 = sf * cstate + si * tg;
        cstate = cc2;
        float cc = fminf(fmaxf(cc2, -30.f), 30.f);
        float ec = __expf(-2.f * cc);
        float th = __fdividef(1.f - ec, 1.f + ec);
        float h = so * th;
        hfl[slot * 256 + j] = f2bf(h);
        int pk = __builtin_amdgcn_cvt_pk_fp8_f32(h, h, 0, false);
        nxt[j] = (unsigned char)(pk & 0xff);
      }
      __syncthreads();
    }
    // chunk end: flush h history (coalesced) + install next xg chunk
    if (tid < 256) {
      int trow = tid >> 5;
      int j0 = (tid & 31) << 3;
      uint4 hv = reinterpret_cast<const uint4*>(hfl)[tid];
      *reinterpret_cast<uint4*>(hseq + (size_t)(tbase + trow) * 256 + j0) = hv;
    }
    if (c < 15) {
      reinterpret_cast<uint4*>(xgl)[tid] = xnext;
      __syncthreads();
    }
  }
}

// ---------------- mid v2: 128 blocks x 16 rows: oc -> emi, u,v -> a,c ----------------
__global__ __launch_bounds__(256) void k_mid2(
    const unsigned short* __restrict__ hf16, const unsigned short* __restrict__ hb16,
    const int* __restrict__ bio, const float* __restrict__ bioE,
    const float* __restrict__ emiW, const float* __restrict__ emib,
    const uint4* __restrict__ suPk, const float* __restrict__ sub,
    const uint4* __restrict__ svPk, const float* __restrict__ svb,
    const uint4* __restrict__ w1Pk, const uint4* __restrict__ w2Pk,
    unsigned short* __restrict__ a16, unsigned short* __restrict__ c16,
    float* __restrict__ emi) {
  __shared__ __align__(16) unsigned short oc[16][328];
  __shared__ __align__(16) unsigned short ub[16][136];
  __shared__ __align__(16) unsigned short vb[16][136];
  int r0 = blockIdx.x * 16;
  int tid = threadIdx.x;

  // stage oc = [0.5*(hf+hb) | bioE[bio]], coalesced u32 loads
#pragma unroll
  for (int it = 0; it < 8; ++it) {
    int i = it * 256 + tid;            // 0..2047
    int row = i >> 7, h2 = (i & 127) << 1;
    unsigned int af = *reinterpret_cast<const unsigned int*>(hf16 + (size_t)(r0 + row) * 256 + h2);
    unsigned int ab = *reinterpret_cast<const unsigned int*>(hb16 + (size_t)(r0 + row) * 256 + h2);
    float lo = 0.5f * (bf2f((unsigned short)af) + bf2f((unsigned short)ab));
    float hi = 0.5f * (bf2f((unsigned short)(af >> 16)) + bf2f((unsigned short)(ab >> 16)));
    unsigned int pk = (unsigned int)f2bf(lo) | ((unsigned int)f2bf(hi) << 16);
    *reinterpret_cast<unsigned int*>(&oc[row][h2]) = pk;
  }
#pragma unroll
  for (int it = 0; it < 2; ++it) {
    int i = it * 256 + tid;            // 0..511
    int row = i >> 5, p = (i & 31) << 1;
    int bi = bio[r0 + row];
    float b0 = bioE[bi * 64 + p], b1 = bioE[bi * 64 + p + 1];
    unsigned int pk = (unsigned int)f2bf(b0) | ((unsigned int)f2bf(b1) << 16);
    *reinterpret_cast<unsigned int*>(&oc[row][256 + p]) = pk;
  }
  __syncthreads();

  // emi: 48 dots (16 rows x 3), 4 threads each
  if (tid < 192) {
    int did = tid >> 2, sub4 = tid & 3;
    int row = did / 3, g = did - row * 3;
    const float* ew = emiW + g * 256 + sub4 * 64;
    float av = 0.f;
#pragma unroll
    for (int k = 0; k < 64; ++k) av += bf2f(oc[row][sub4 * 64 + k]) * ew[k];
    av += __shfl_xor(av, 1);
    av += __shfl_xor(av, 2);
    if (sub4 == 0) emi[(size_t)(r0 + row) * 3 + g] = av + emib[g];
  }

  int w = tid >> 6, lane = tid & 63, m = lane & 15, q = lane >> 4;
  // u,v: 16 rows x 128 cols; wave w owns nt = 2w, 2w+1
  {
    f32x4 z = {0.f, 0.f, 0.f, 0.f};
    f32x4 au[2] = {z, z}, av2[2] = {z, z};
    for (int kt = 0; kt < 10; ++kt) {
      uint4 a4 = *reinterpret_cast<const uint4*>(&oc[m][(kt << 5) + (q << 3)]);
      short8 af = __builtin_bit_cast(short8, a4);
#pragma unroll
      for (int d = 0; d < 2; ++d) {
        int nt = (w << 1) + d;
        uint4 bu = suPk[(size_t)(nt * 10 + kt) * 64 + lane];
        uint4 bv = svPk[(size_t)(nt * 10 + kt) * 64 + lane];
        au[d] = __builtin_amdgcn_mfma_f32_16x16x32_bf16(af, __builtin_bit_cast(short8, bu), au[d], 0, 0, 0);
        av2[d] = __builtin_amdgcn_mfma_f32_16x16x32_bf16(af, __builtin_bit_cast(short8, bv), av2[d], 0, 0, 0);
      }
    }
#pragma unroll
    for (int d = 0; d < 2; ++d) {
      int col = ((w << 1) + d) * 16 + m;
      float bu = sub[col], bv = svb[col];
#pragma unroll
      for (int reg = 0; reg < 4; ++reg) {
        int row = (q << 2) + reg;
        ub[row][col] = f2bf(fmaxf(au[d][reg] + bu, 0.f));
        vb[row][col] = f2bf(fmaxf(av2[d][reg] + bv, 0.f));
      }
    }
  }
  __syncthreads();

  // a = u@W1^T, c = v@W2^T
  {
    f32x4 z = {0.f, 0.f, 0.f, 0.f};
    f32x4 aa[2] = {z, z}, cc[2] = {z, z};
    for (int kt = 0; kt < 4; ++kt) {
      uint4 ua = *reinterpret_cast<const uint4*>(&ub[m][(kt << 5) + (q << 3)]);
      uint4 va = *reinterpret_cast<const uint4*>(&vb[m][(kt << 5) + (q << 3)]);
      short8 uf = __builtin_bit_cast(short8, ua);
      short8 vf = __builtin_bit_cast(short8, va);
#pragma unroll
      for (int d = 0; d < 2; ++d) {
        int nt = (w << 1) + d;
        uint4 b1 = w1Pk[(size_t)((nt << 2) + kt) * 64 + lane];
        uint4 b2 = w2Pk[(size_t)((nt << 2) + kt) * 64 + lane];
        aa[d] = __builtin_amdgcn_mfma_f32_16x16x32_bf16(uf, __builtin_bit_cast(short8, b1), aa[d], 0, 0, 0);
        cc[d] = __builtin_amdgcn_mfma_f32_16x16x32_bf16(vf, __builtin_bit_cast(short8, b2), cc[d], 0, 0, 0);
      }
    }
#pragma unroll
    for (int d = 0; d < 2; ++d) {
      int col = ((w << 1) + d) * 16 + m;
#pragma unroll
      for (int reg = 0; reg < 4; ++reg) {
        int row = r0 + (q << 2) + reg;
        a16[(size_t)row * 128 + col] = f2bf(aa[d][reg]);
        c16[(size_t)row * 128 + col] = f2bf(cc[d][reg]);
      }
    }
  }
}

// ---------------- fused loss: sel (0..1023) + crf (1024..1039) + finalize ----------
__global__ __launch_bounds__(256) void k_loss(
    const unsigned short* __restrict__ a16, const unsigned short* __restrict__ c16,
    const float* __restrict__ suvb, const float* __restrict__ rel,
    const float* __restrict__ y, const int* __restrict__ tok,
    const float* __restrict__ emi, const int* __restrict__ bio,
    const float* __restrict__ cstart, const float* __restrict__ cend,
    const float* __restrict__ ctrans,
    float* __restrict__ acc, float* __restrict__ out) {
  int blk = blockIdx.x;
  int tid = threadIdx.x;
  if (blk < 1024) {
    __shared__ unsigned short alds[128][136];
    __shared__ float cbs[2][128];
    __shared__ float red[4];
    int b = blk >> 6;
    int ip = blk & 63;
    int hh = tid & 127;
    int half = tid >> 7;
    // coalesced staging: row-major global reads, transposed LDS writes
#pragma unroll
    for (int it = 0; it < 32; ++it) {
      int idx = it * 256 + tid;        // 0..8191
      int jrow = idx >> 6;
      int h2 = (idx & 63) << 1;
      unsigned int av = *reinterpret_cast<const unsigned int*>(
          a16 + ((size_t)(b << 7) + jrow) * 128 + h2);
      alds[h2][jrow] = (unsigned short)av;
      alds[h2 + 1][jrow] = (unsigned short)(av >> 16);
    }
    {
      int i = (ip << 1) + half;
      cbs[half][hh] = bf2f(c16[(size_t)((b << 7) + i) * 128 + hh]) + suvb[hh];
    }
    __syncthreads();
    int i = (ip << 1) + half;
    int j = hh;
    float lg[25];
#pragma unroll
    for (int r = 0; r < 25; ++r) lg[r] = 0.f;
    for (int h = 0; h < 128; ++h) {
      float av = bf2f(alds[h][j]);
      float uv = fmaxf(av + cbs[half][h], 0.f);
#pragma unroll
      for (int r = 0; r < 25; ++r) lg[r] += uv * rel[r * 128 + h];
    }
    float mi = (tok[(b << 7) + i] != 0) ? 1.f : 0.f;
    float mj = (tok[(b << 7) + j] != 0) ? 1.f : 0.f;
    const float* yp = y + (size_t)((b << 7) + i) * 3200 + j;
    float bs = 0.f;
#pragma unroll
    for (int r = 0; r < 25; ++r) {
      float x = lg[r];
      float yv = yp[r * 128];
      bs += fmaxf(x, 0.f) - x * yv + __logf(1.f + __expf(-fabsf(x)));
    }
    bs *= mi * mj;
#pragma unroll
    for (int off = 32; off; off >>= 1) bs += __shfl_down(bs, off);
    if ((tid & 63) == 0) red[tid >> 6] = bs;
    __syncthreads();
    if (tid == 0) atomicAdd(&acc[0], red[0] + red[1] + red[2] + red[3]);
  } else {
    __shared__ float elds[128][4];
    __shared__ float msk[128];
    __shared__ int biol[128];
    __shared__ float r_t[2], r_m[2];
    int b = blk - 1024;
    int t = tid;
    if (t < 128) {
      biol[t] = bio[b * 128 + t];
      msk[t] = (tok[b * 128 + t] != 0) ? 1.f : 0.f;
#pragma unroll
      for (int g = 0; g < 3; ++g) elds[t][g] = emi[(b * 128 + t) * 3 + g];
    }
    __syncthreads();
    if (t < 128) {
      float m = msk[t];
      float term;
      if (t == 0)
        term = cstart[biol[0]] + elds[0][biol[0]];
      else
        term = (ctrans[biol[t - 1] * 3 + biol[t]] + elds[t][biol[t]]) * m;
      float ms = m;
#pragma unroll
      for (int off = 32; off; off >>= 1) {
        term += __shfl_down(term, off);
        ms += __shfl_down(ms, off);
      }
      if ((t & 63) == 0) { r_t[t >> 6] = term; r_m[t >> 6] = ms; }
    }
    __syncthreads();
    if (t == 0) {
      float num = r_t[0] + r_t[1];
      float msum = r_m[0] + r_m[1];
      int se = (int)msum - 1;
      if (se < 0) se = 0;
      num += cend[biol[se]];
      float tr[9];
#pragma unroll
      for (int i2 = 0; i2 < 9; ++i2) tr[i2] = ctrans[i2];
      float s0 = cstart[0] + elds[0][0];
      float s1 = cstart[1] + elds[0][1];
      float s2 = cstart[2] + elds[0][2];
      for (int tt = 1; tt < 128; ++tt) {
        float a0, a1, a2, mx, n0, n1, n2;
        a0 = s0 + tr[0]; a1 = s1 + tr[3]; a2 = s2 + tr[6];
        mx = fmaxf(a0, fmaxf(a1, a2));
        n0 = mx + __logf(__expf(a0 - mx) + __expf(a1 - mx) + __expf(a2 - mx)) + elds[tt][0];
        a0 = s0 + tr[1]; a1 = s1 + tr[4]; a2 = s2 + tr[7];
        mx = fmaxf(a0, fmaxf(a1, a2));
        n1 = mx + __logf(__expf(a0 - mx) + __expf(a1 - mx) + __expf(a2 - mx)) + elds[tt][1];
        a0 = s0 + tr[2]; a1 = s1 + tr[5]; a2 = s2 + tr[8];
        mx = fmaxf(a0, fmaxf(a1, a2));
        n2 = mx + __logf(__expf(a0 - mx) + __expf(a1 - mx) + __expf(a2 - mx)) + elds[tt][2];
        if (msk[tt] != 0.f) { s0 = n0; s1 = n1; s2 = n2; }
      }
      float a0 = s0 + cend[0], a1 = s1 + cend[1], a2 = s2 + cend[2];
      float mx = fmaxf(a0, fmaxf(a1, a2));
      float den = mx + __logf(__expf(a0 - mx) + __expf(a1 - mx) + __expf(a2 - mx));
      atomicAdd(&acc[1], num - den);
      atomicAdd(&acc[2], msum);
    }
  }
  if (tid == 0) {
    __threadfence();
    unsigned old = atomicAdd((unsigned int*)(acc + 5), 1u);
    if (old == 1039u) {
      __threadfence();
      float s0 = atomicAdd(&acc[0], 0.f);
      float s1 = atomicAdd(&acc[1], 0.f);
      float s2 = atomicAdd(&acc[2], 0.f);
      out[0] = -(s1 * (1.f / 16.f)) + s0 / s2;
    }
  }
}

// ---------------- host launcher ----------------
extern "C" void kernel_launch(void* const* d_in, const int* in_sizes, int n_in,
                              void* d_out, int out_size, void* d_ws, size_t ws_size,
                              hipStream_t stream) {
  const int* tokens = (const int*)d_in[0];
  const int* bio = (const int*)d_in[1];
  const float* selg = (const float*)d_in[2];
  const float* wemb = (const float*)d_in[3];
  const float* Wihf = (const float*)d_in[4];
  const float* Whhf = (const float*)d_in[5];
  const float* bf = (const float*)d_in[6];
  const float* Wihb = (const float*)d_in[7];
  const float* Whhb = (const float*)d_in[8];
  const float* bb = (const float*)d_in[9];
  const float* emiW = (const float*)d_in[10];
  const float* emib = (const float*)d_in[11];
  const float* bioE = (const float*)d_in[12];
  const float* suW = (const float*)d_in[13];
  const float* sub = (const float*)d_in[14];
  const float* svW = (const float*)d_in[15];
  const float* svb = (const float*)d_in[16];
  const float* suvW = (const float*)d_in[17];
  const float* suvb = (const float*)d_in[18];
  const float* rel = (const float*)d_in[19];
  const float* cstart = (const float*)d_in[20];
  const float* cend = (const float*)d_in[21];
  const float* ctrans = (const float*)d_in[22];

  float* ws = (float*)d_ws;
  float* xgf16 = ws;                         // 1048576 f (2048x1024 bf16)
  float* xgb16 = xgf16 + 1048576;            // 1048576
  float* hf16 = xgb16 + 1048576;             // 262144 f (2048x256 bf16)
  float* hb16 = hf16 + 262144;               // 262144
  float* a16 = hb16 + 262144;                // 131072 f (2048x128 bf16)
  float* c16 = a16 + 131072;                 // 131072
  float* emi = c16 + 131072;                 // 6144
  float* wpk8f = emi + 6144;                 // 65536 f (256 KB fp8 K=128 frags)
  float* wpk8b = wpk8f + 65536;              // 65536
  float* wihfPk = wpk8b + 65536;             // 131072 f
  float* wihbPk = wihfPk + 131072;           // 131072
  float* suPk = wihbPk + 131072;             // 20480 f
  float* svPk = suPk + 20480;                // 20480
  float* w1Pk = svPk + 20480;                // 8192 f
  float* w2Pk = w1Pk + 8192;                 // 8192
  float* acc = w2Pk + 8192;                  // 16

  k_setup<<<569, 256, 0, stream>>>(
      Whhf, (unsigned int*)wpk8f, Whhb, (unsigned int*)wpk8b,
      Wihf, (uint4*)wihfPk, Wihb, (uint4*)wihbPk,
      suW, (uint4*)suPk, svW, (uint4*)svPk,
      suvW, (uint4*)w1Pk, (uint4*)w2Pk, acc);

  k_xg<<<dim3(16, 32, 2), 256, 0, stream>>>(
      tokens, wemb,
      (const uint4*)wihfPk, bf, (unsigned short*)xgf16,
      (const uint4*)wihbPk, bb, (unsigned short*)xgb16);

  k_lstm8<<<32, 1024, 0, stream>>>(
      (const unsigned short*)xgf16, (const unsigned short*)xgb16,
      (const unsigned int*)wpk8f, (const unsigned int*)wpk8b,
      (unsigned short*)hf16, (unsigned short*)hb16);

  k_mid2<<<128, 256, 0, stream>>>(
      (const unsigned short*)hf16, (const unsigned short*)hb16,
      bio, bioE, emiW, emib,
      (const uint4*)suPk, sub, (const uint4*)svPk, svb,
      (const uint4*)w1Pk, (const uint4*)w2Pk,
      (unsigned short*)a16, (unsigned short*)c16, emi);

  k_loss<<<1040, 256, 0, stream>>>((const unsigned short*)a16, (const unsigned short*)c16,
                                   suvb, rel, selg, tokens, emi, bio,
                                   cstart, cend, ctrans, acc, (float*)d_out);
}